// Round 11
// baseline (688.829 us; speedup 1.0000x reference)
//
#include <hip/hip_runtime.h>

// Parallel-beam forward projection (Radon transform), LDS-tiled, v4.
// x: [B,1,512,512] f32 -> sino: [B,1,512,512] f32
// Block = (view, batch, 64-bin s-tile); 16 chunks of 32 t-steps.
// v4: smaller tile (76 x 80, pitch 81, ~25.6 KB LDS) -> 6 blocks/CU = 24 waves
//     (was 4 blocks/16 waves) to overlap the VALU and DS pipes (dependency-bound).

#define N_IMG 512
#define N_VIEWS 512
#define N_BINS 512
#define SB 64      // bins per block
#define TC 32      // t-steps per chunk
#define NCH (N_IMG / TC)       // 16
#define TDY 76     // staged rows (y span <= 73.2)
#define TDX 80     // staged cols (x span <= 76.2, 4-aligned)
#define PITCH 81   // odd pitch (81 mod 32 = 17): spreads banks for near-axis angles
#define GPR (TDX / 4)          // 20 granules per row
#define NGRAN (TDY * GPR)      // 1520 granules

__global__ __launch_bounds__(256) void radon_fp_tiled4(const float* __restrict__ img,
                                                       float* __restrict__ out) {
    __shared__ float tile[TDY * PITCH];
    __shared__ float red[4][SB];

    const int v     = blockIdx.x;   // view
    const int b     = blockIdx.y;   // batch
    const int stile = blockIdx.z;   // s-tile (0..7)
    const int tid   = threadIdx.x;
    const int binl  = tid & 63;     // bin within tile
    const int g     = tid >> 6;     // t-group == wave id (0..3)

    const float dth = (float)(3.14159265358979323846 / (double)N_VIEWS);
    float st, ct;
    sincosf((float)v * dth, &st, &ct);

    const float c = (float)(N_IMG - 1) * 0.5f;              // 255.5
    const float s = (float)(stile * SB + binl) - (float)(N_BINS - 1) * 0.5f;

    const float* __restrict__ im = img + (size_t)b * (N_IMG * N_IMG);

    // block-uniform s-range for bbox
    const float sA  = (float)(stile * SB) - (float)(N_BINS - 1) * 0.5f;
    const float sBv = sA + (float)(SB - 1);

    float acc = 0.0f;

    for (int ch = 0; ch < NCH; ++ch) {
        // ---- bounding box of this (s-tile, t-chunk) footprint (block-uniform) ----
        const float tA = (float)(ch * TC) - (float)(N_IMG - 1) * 0.5f;
        const float tB = tA + (float)(TC - 1);

        const float xs[4] = { sA * ct - tA * st, sA * ct - tB * st,
                              sBv * ct - tA * st, sBv * ct - tB * st };
        const float ys[4] = { sA * st + tA * ct, sA * st + tB * ct,
                              sBv * st + tA * ct, sBv * st + tB * ct };
        const float xmin = fminf(fminf(xs[0], xs[1]), fminf(xs[2], xs[3])) + c;
        const float ymin = fminf(fminf(ys[0], ys[1]), fminf(ys[2], ys[3])) + c;
        const int X0 = ((int)floorf(xmin) - 1) & ~3;   // -1 margin, 4-aligned down
        const int Y0 = (int)floorf(ymin) - 1;

        __syncthreads();   // previous chunk's reads done before overwrite

        // ---- stage TDY x TDX cells (1520 float4 granules), zero outside ----
        const bool interior = (X0 >= 0) & (X0 + TDX <= N_IMG) &
                              (Y0 >= 0) & (Y0 + TDY <= N_IMG);
        if (interior) {
#pragma unroll
            for (int k = 0; k < 6; ++k) {
                const int gi = tid + k * 256;
                if (k < 5 || gi < NGRAN) {            // 5*256=1280 < 1520: guard last only
                    const int r  = gi / GPR;          // compile-time magic div
                    const int c4 = (gi - r * GPR) * 4;
                    const float4 vv = *reinterpret_cast<const float4*>(
                        im + ((Y0 + r) << 9) + X0 + c4);
                    float* dst = &tile[r * PITCH + c4];
                    dst[0] = vv.x; dst[1] = vv.y; dst[2] = vv.z; dst[3] = vv.w;
                }
            }
        } else {
            // edge path: per-element clamp+zero (exact reference semantics)
#pragma unroll
            for (int k = 0; k < 6; ++k) {
                const int gi = tid + k * 256;
                if (k < 5 || gi < NGRAN) {
                    const int r  = gi / GPR;
                    const int c4 = (gi - r * GPR) * 4;
                    const int gy = Y0 + r;
                    const bool rowok = ((unsigned)gy < (unsigned)N_IMG);
                    float* dst = &tile[r * PITCH + c4];
#pragma unroll
                    for (int q = 0; q < 4; ++q) {
                        const int gx = X0 + c4 + q;
                        float val = 0.0f;
                        if (rowok && (unsigned)gx < (unsigned)N_IMG)
                            val = im[(gy << 9) + gx];
                        dst[q] = val;
                    }
                }
            }
        }
        __syncthreads();

        // ---- 8 t-steps per thread from LDS ----
        const float xbase = fmaf(s, ct, c - (float)X0);
        const float ybase = fmaf(s, st, c - (float)Y0);
        const float tb0 = (float)(ch * TC + g * 8) - (float)(N_IMG - 1) * 0.5f;
        const float xg = fmaf(-tb0, st, xbase);
        const float yg = fmaf(tb0, ct, ybase);
#pragma unroll
        for (int j = 0; j < 8; ++j) {
            const float xl = fmaf(-(float)j, st, xg);
            const float yl = fmaf((float)j, ct, yg);
            const float x0 = floorf(xl);
            const float y0 = floorf(yl);
            const float wx = xl - x0;
            const float wy = yl - y0;
            // exact integer index: y0*81 + x0 <= 6156 < 2^24
            const int e = (int)fmaf(y0, (float)PITCH, x0);
            const float* p = &tile[e];
            const float v00 = p[0];
            const float v10 = p[1];
            const float v01 = p[PITCH];
            const float v11 = p[PITCH + 1];
            const float a0 = fmaf(v10 - v00, wx, v00);
            const float a1 = fmaf(v11 - v01, wx, v01);
            acc += fmaf(a1 - a0, wy, a0);
        }
    }

    // ---- reduce the 4 t-groups per bin ----
    red[g][binl] = acc;
    __syncthreads();
    if (tid < SB) {
        const float r0 = red[0][tid] + red[1][tid] + red[2][tid] + red[3][tid];
        out[((size_t)(b * N_VIEWS + v) << 9) + stile * SB + tid] = r0;
    }
}

extern "C" void kernel_launch(void* const* d_in, const int* in_sizes, int n_in,
                              void* d_out, int out_size, void* d_ws, size_t ws_size,
                              hipStream_t stream) {
    const float* img = (const float*)d_in[0];
    float* out = (float*)d_out;
    const int B = in_sizes[0] / (N_IMG * N_IMG);
    dim3 grid(N_VIEWS, B, N_BINS / SB);
    radon_fp_tiled4<<<grid, 256, 0, stream>>>(img, out);
}

// Round 14
// 647.661 us; speedup vs baseline: 1.0636x; 1.0636x over previous
//
#include <hip/hip_runtime.h>

// Parallel-beam forward projection (Radon transform), LDS-tiled, v5.
// x: [B,1,512,512] f32 -> sino: [B,1,512,512] f32
// Block = (view, batch, 64-bin s-tile); 16 chunks of 32 t-steps; tile 76x80,
// pitch 81 (~24KB LDS, 6 blocks/CU).
// v5: (a) conflict-free two-phase staging writes (bank = 17r+4g spread);
//     (b) 8x8 (s,t) lane tile for reads: lane = lt*8+ls samples bin(ls) at
//         t-step(lt) -> 2D bank spread, worst-case 4-way instead of 32-way;
//     (c) per-bin totals via 3x shfl_xor, red[] LDS + final barrier deleted.

#define N_IMG 512
#define N_VIEWS 512
#define N_BINS 512
#define SB 64      // bins per block
#define TC 32      // t-steps per chunk
#define NCH (N_IMG / TC)       // 16
#define TDY 76     // staged rows  (y span <= 73.2 + margins)
#define TDX 80     // staged cols  (x span <= 76.2 incl. 4-align slack)
#define PITCH 81   // odd pitch, 81 mod 32 = 17 (unit gcd with 32)

__global__ __launch_bounds__(256) void radon_fp_tiled5(const float* __restrict__ img,
                                                       float* __restrict__ out) {
    __shared__ float tile[TDY * PITCH];

    const int v     = blockIdx.x;   // view
    const int b     = blockIdx.y;   // batch
    const int stile = blockIdx.z;   // s-tile (0..7)
    const int tid   = threadIdx.x;
    const int lane  = tid & 63;
    const int w     = tid >> 6;     // wave id (0..3)
    const int ls    = lane & 7;     // bin-offset within wave (0..7)
    const int lt    = lane >> 3;    // t-offset within chunk-subset (0..7)

    const float dth = (float)(3.14159265358979323846 / (double)N_VIEWS);
    float st, ct;
    sincosf((float)v * dth, &st, &ct);

    const float c = (float)(N_IMG - 1) * 0.5f;              // 255.5
    // two bins per thread: bin0 = w*16 + ls, bin1 = bin0 + 8
    const float s0 = (float)(stile * SB + w * 16 + ls) - (float)(N_BINS - 1) * 0.5f;

    const float* __restrict__ im = img + (size_t)b * (N_IMG * N_IMG);

    // block-uniform s-range for bbox
    const float sA  = (float)(stile * SB) - (float)(N_BINS - 1) * 0.5f;
    const float sBv = sA + (float)(SB - 1);

    // staging lane maps (block-level)
    const int rA = tid >> 4;          // phase A: 16 rows x 16 gcols
    const int gA = tid & 15;
    const int rB = tid >> 2;          // phase B: 64 rows x 4 gcols (16..19)
    const int gB = 16 + (tid & 3);

    float acc0 = 0.0f, acc1 = 0.0f;

    for (int ch = 0; ch < NCH; ++ch) {
        // ---- bounding box of this (s-tile, t-chunk) footprint (block-uniform) ----
        const float tA = (float)(ch * TC) - (float)(N_IMG - 1) * 0.5f;
        const float tB = tA + (float)(TC - 1);

        const float xs[4] = { sA * ct - tA * st, sA * ct - tB * st,
                              sBv * ct - tA * st, sBv * ct - tB * st };
        const float ys[4] = { sA * st + tA * ct, sA * st + tB * ct,
                              sBv * st + tA * ct, sBv * st + tB * ct };
        const float xmin = fminf(fminf(xs[0], xs[1]), fminf(xs[2], xs[3])) + c;
        const float ymin = fminf(fminf(ys[0], ys[1]), fminf(ys[2], ys[3])) + c;
        const int X0 = ((int)floorf(xmin) - 1) & ~3;   // -1 margin, 4-aligned down
        const int Y0 = (int)floorf(ymin) - 1;

        __syncthreads();   // previous chunk's reads done before overwrite

        // ---- stage TDY x TDX cells, zero outside (two conflict-free phases) ----
        const bool interior = (X0 >= 0) & (X0 + TDX <= N_IMG) &
                              (Y0 >= 0) & (Y0 + TDY <= N_IMG);
        if (interior) {
#pragma unroll
            for (int k = 0; k < 5; ++k) {              // phase A: gcols 0..15
                const int r = rA + k * 16;
                if (k < 4 || r < TDY) {
                    const float4 vv = *reinterpret_cast<const float4*>(
                        im + ((Y0 + r) << 9) + X0 + 4 * gA);
                    float* dst = &tile[r * PITCH + 4 * gA];
                    dst[0] = vv.x; dst[1] = vv.y; dst[2] = vv.z; dst[3] = vv.w;
                }
            }
#pragma unroll
            for (int k = 0; k < 2; ++k) {              // phase B: gcols 16..19
                const int r = rB + k * 64;
                if (k == 0 || r < TDY) {
                    const float4 vv = *reinterpret_cast<const float4*>(
                        im + ((Y0 + r) << 9) + X0 + 4 * gB);
                    float* dst = &tile[r * PITCH + 4 * gB];
                    dst[0] = vv.x; dst[1] = vv.y; dst[2] = vv.z; dst[3] = vv.w;
                }
            }
        } else {
            // edge path: same mapping, per-element clamp+zero (exact semantics)
#pragma unroll
            for (int k = 0; k < 5; ++k) {
                const int r = rA + k * 16;
                if (k < 4 || r < TDY) {
                    const int gy = Y0 + r;
                    const bool rowok = ((unsigned)gy < (unsigned)N_IMG);
                    float* dst = &tile[r * PITCH + 4 * gA];
#pragma unroll
                    for (int q = 0; q < 4; ++q) {
                        const int gx = X0 + 4 * gA + q;
                        float val = 0.0f;
                        if (rowok && (unsigned)gx < (unsigned)N_IMG)
                            val = im[(gy << 9) + gx];
                        dst[q] = val;
                    }
                }
            }
#pragma unroll
            for (int k = 0; k < 2; ++k) {
                const int r = rB + k * 64;
                if (k == 0 || r < TDY) {
                    const int gy = Y0 + r;
                    const bool rowok = ((unsigned)gy < (unsigned)N_IMG);
                    float* dst = &tile[r * PITCH + 4 * gB];
#pragma unroll
                    for (int q = 0; q < 4; ++q) {
                        const int gx = X0 + 4 * gB + q;
                        float val = 0.0f;
                        if (rowok && (unsigned)gx < (unsigned)N_IMG)
                            val = im[(gy << 9) + gx];
                        dst[q] = val;
                    }
                }
            }
        }
        __syncthreads();

        // ---- compute: 2 bins x 4 j-steps per thread (t = ch*32 + j*8 + lt) ----
        const float cX = c - (float)X0;
        const float cY = c - (float)Y0;
        const float xg0 = fmaf(s0, ct, cX);
        const float yg0 = fmaf(s0, st, cY);
        const float xg1 = fmaf(8.0f, ct, xg0);     // bin + 8
        const float yg1 = fmaf(8.0f, st, yg0);
        const float tb0 = (float)(ch * TC + lt) - (float)(N_IMG - 1) * 0.5f;
        const float xa0 = fmaf(-tb0, st, xg0), ya0 = fmaf(tb0, ct, yg0);
        const float xa1 = fmaf(-tb0, st, xg1), ya1 = fmaf(tb0, ct, yg1);
#pragma unroll
        for (int j = 0; j < 4; ++j) {
            const float jj = (float)(8 * j);
            {
                const float xl = fmaf(-jj, st, xa0);
                const float yl = fmaf(jj, ct, ya0);
                const float x0 = floorf(xl), y0 = floorf(yl);
                const float wx = xl - x0, wy = yl - y0;
                const int e = (int)fmaf(y0, (float)PITCH, x0);   // exact, < 2^24
                const float* p = &tile[e];
                const float a0 = fmaf(p[1] - p[0], wx, p[0]);
                const float a1 = fmaf(p[PITCH + 1] - p[PITCH], wx, p[PITCH]);
                acc0 += fmaf(a1 - a0, wy, a0);
            }
            {
                const float xl = fmaf(-jj, st, xa1);
                const float yl = fmaf(jj, ct, ya1);
                const float x0 = floorf(xl), y0 = floorf(yl);
                const float wx = xl - x0, wy = yl - y0;
                const int e = (int)fmaf(y0, (float)PITCH, x0);
                const float* p = &tile[e];
                const float a0 = fmaf(p[1] - p[0], wx, p[0]);
                const float a1 = fmaf(p[PITCH + 1] - p[PITCH], wx, p[PITCH]);
                acc1 += fmaf(a1 - a0, wy, a0);
            }
        }
    }

    // ---- reduce across the 8 t-lanes (lane bits 3..5) ----
    acc0 += __shfl_xor(acc0, 8);  acc0 += __shfl_xor(acc0, 16);  acc0 += __shfl_xor(acc0, 32);
    acc1 += __shfl_xor(acc1, 8);  acc1 += __shfl_xor(acc1, 16);  acc1 += __shfl_xor(acc1, 32);

    if (lane < 16) {
        const float val = (lane < 8) ? acc0 : acc1;
        const int bin = stile * SB + w * 16 + (lane & 7) + (lane & 8);
        out[((size_t)(b * N_VIEWS + v) << 9) + bin] = val;
    }
}

extern "C" void kernel_launch(void* const* d_in, const int* in_sizes, int n_in,
                              void* d_out, int out_size, void* d_ws, size_t ws_size,
                              hipStream_t stream) {
    const float* img = (const float*)d_in[0];
    float* out = (float*)d_out;
    const int B = in_sizes[0] / (N_IMG * N_IMG);
    dim3 grid(N_VIEWS, B, N_BINS / SB);
    radon_fp_tiled5<<<grid, 256, 0, stream>>>(img, out);
}